// Round 2
// baseline (688.945 us; speedup 1.0000x reference)
//
#include <hip/hip_runtime.h>
#include <hip/hip_bf16.h>
#include <math.h>

#define NHEADS 4
#define DOUT 16
#define EDIM 5

// ---------------------------------------------------------------------------
// K1: feat_p = feat @ W_fc  (N x 64 @ 64 x 64), fused el/er attention dots.
// One wave (64 lanes) per node; lane j owns output feature j (= h*16+d).
// W_fc staged in LDS (16 KB). feat row broadcast via shfl.
// ---------------------------------------------------------------------------
__global__ __launch_bounds__(256) void node_proj_kernel(
    const float* __restrict__ feat, const float* __restrict__ W_fc,
    const float* __restrict__ attn_l, const float* __restrict__ attn_r,
    float* __restrict__ feat_p, float* __restrict__ el_er, int N) {
  __shared__ float wfc[64 * 64];
  for (int i = threadIdx.x; i < 64 * 64; i += 256) wfc[i] = W_fc[i];
  __syncthreads();
  const int wid  = threadIdx.x >> 6;
  const int lane = threadIdx.x & 63;
  const int n = blockIdx.x * 4 + wid;
  if (n >= N) return;

  const float f = feat[(size_t)n * 64 + lane];
  float acc = 0.f;
#pragma unroll
  for (int k = 0; k < 64; ++k) {
    const float fk = __shfl(f, k);
    acc += fk * wfc[k * 64 + lane];
  }
  feat_p[(size_t)n * 64 + lane] = acc;

  // el[h] = sum_d feat_p[h][d]*attn_l[h][d]; attn flat index == lane
  float al = acc * attn_l[lane];
  float ar = acc * attn_r[lane];
#pragma unroll
  for (int off = 1; off < 16; off <<= 1) {
    al += __shfl_xor(al, off);
    ar += __shfl_xor(ar, off);
  }
  if ((lane & 15) == 0) {
    const int h = lane >> 4;
    el_er[(size_t)n * 8 + h]     = al;
    el_er[(size_t)n * 8 + 4 + h] = ar;
  }
}

// ---------------------------------------------------------------------------
// K2: per-edge logits (leaky-relu(el[src]+er[dst]+ee)) + dst histogram.
// The histogram atomic's return value IS the edge's rank within its dst
// segment -> store it so the CSR scatter needs no second atomic pass.
// ---------------------------------------------------------------------------
__global__ __launch_bounds__(256) void edge_logits_hist_kernel(
    const float* __restrict__ edge_fea, const int* __restrict__ src,
    const int* __restrict__ dst, const float* __restrict__ el_er,
    const float* __restrict__ W_edg, const float* __restrict__ b_edg,
    const float* __restrict__ attn_edg, float* __restrict__ e_logits,
    int* __restrict__ deg, int* __restrict__ rank, int E) {
  const int e = blockIdx.x * blockDim.x + threadIdx.x;
  if (e >= E) return;
  const int s = src[e];
  const int d = dst[e];
  rank[e] = atomicAdd(&deg[d], 1);

  float ef[5];
#pragma unroll
  for (int k = 0; k < 5; ++k) ef[k] = edge_fea[(size_t)e * 5 + k];

  const float4 elv = *(const float4*)(el_er + (size_t)s * 8);
  const float4 erv = *(const float4*)(el_er + (size_t)d * 8 + 4);
  const float elh[4] = {elv.x, elv.y, elv.z, elv.w};
  const float erh[4] = {erv.x, erv.y, erv.z, erv.w};

  float out[4];
#pragma unroll
  for (int h = 0; h < 4; ++h) {
    float ee = 0.f;
#pragma unroll
    for (int ed = 0; ed < 5; ++ed) {
      float ep = b_edg[h * 5 + ed];
#pragma unroll
      for (int k = 0; k < 5; ++k) ep += ef[k] * W_edg[k * 20 + h * 5 + ed];
      ee += ep * attn_edg[h * 5 + ed];
    }
    const float lg = elh[h] + erh[h] + ee;
    out[h] = (lg > 0.f) ? lg : 0.2f * lg;
  }
  *(float4*)(e_logits + (size_t)e * 4) = make_float4(out[0], out[1], out[2], out[3]);
}

// ---------------------------------------------------------------------------
// K3: single-block exclusive scan over deg[N] -> row_off[N+1].
// 1024 threads = 16 waves; shfl-based wave scans, 2 barriers per 1024 chunk.
// ---------------------------------------------------------------------------
__global__ __launch_bounds__(1024) void scan_kernel(
    const int* __restrict__ deg, int* __restrict__ row_off, int N) {
  __shared__ int wsum[16];
  __shared__ int carry_s;
  const int tid = threadIdx.x;
  const int lane = tid & 63;
  const int wid = tid >> 6;
  if (tid == 0) carry_s = 0;
  __syncthreads();
  const int nchunk = (N + 1023) / 1024;
  for (int c = 0; c < nchunk; ++c) {
    const int i = c * 1024 + tid;
    const int v = (i < N) ? deg[i] : 0;
    // inclusive wave scan
    int x = v;
#pragma unroll
    for (int off = 1; off < 64; off <<= 1) {
      const int t = __shfl_up(x, off);
      if (lane >= off) x += t;
    }
    if (lane == 63) wsum[wid] = x;
    __syncthreads();
    if (wid == 0 && lane < 16) {
      int s = wsum[lane];
#pragma unroll
      for (int off = 1; off < 16; off <<= 1) {
        const int t = __shfl_up(s, off);
        if (lane >= off) s += t;
      }
      wsum[lane] = s;  // inclusive over wave sums
    }
    __syncthreads();
    const int wbase = (wid > 0) ? wsum[wid - 1] : 0;
    const int carry = carry_s;
    if (i < N) row_off[i] = carry + wbase + x - v;  // exclusive
    const int total = wsum[15];
    __syncthreads();
    if (tid == 0) carry_s = carry + total;
    __syncthreads();
  }
  if (tid == 0) row_off[N] = carry_s;
}

// ---------------------------------------------------------------------------
// K4: scatter edge ids into CSR order (no atomics — rank precomputed in K2).
// ---------------------------------------------------------------------------
__global__ __launch_bounds__(256) void scatter_kernel(
    const int* __restrict__ dst, const int* __restrict__ row_off,
    const int* __restrict__ rank, int* __restrict__ perm, int E) {
  const int e = blockIdx.x * blockDim.x + threadIdx.x;
  if (e >= E) return;
  perm[row_off[dst[e]] + rank[e]] = e;
}

// ---------------------------------------------------------------------------
// K5: one wave per destination node.
//   pass 1: per-head max of logits (lane-parallel, shfl_xor reduce)
//   pass 2: p = exp(e-m); z += p; ft += p*feat_p[src]; ftf += p*edge_p
//   epilogue: normalize, fused [21]x[21,16] per-head matmul via shfl, write.
// ---------------------------------------------------------------------------
__global__ __launch_bounds__(256) void aggregate_kernel(
    const float* __restrict__ feat_p, const float* __restrict__ e_logits,
    const float* __restrict__ edge_fea, const int* __restrict__ src,
    const int* __restrict__ row_off, const int* __restrict__ perm,
    const float* __restrict__ W_edg, const float* __restrict__ b_edg,
    const float* __restrict__ W_out, const float* __restrict__ b_out,
    const float* __restrict__ bias, float* __restrict__ out, int N) {
  const int wid  = threadIdx.x >> 6;
  const int lane = threadIdx.x & 63;
  const int n = blockIdx.x * 4 + wid;
  if (n >= N) return;
  const int h = lane >> 4;
  const int d = lane & 15;

  // per-lane W_edg column (only meaningful for d < 5)
  float wcol[5];
  float be = 0.f;
  if (d < 5) {
    be = b_edg[h * 5 + d];
#pragma unroll
    for (int k = 0; k < 5; ++k) wcol[k] = W_edg[k * 20 + h * 5 + d];
  }

  const int beg = row_off[n];
  const int end = row_off[n + 1];

  // ---- pass 1: per-head max ----
  float mx0 = -INFINITY, mx1 = -INFINITY, mx2 = -INFINITY, mx3 = -INFINITY;
  for (int i = beg + lane; i < end; i += 64) {
    const int e = perm[i];
    const float4 lg = *(const float4*)(e_logits + (size_t)e * 4);
    mx0 = fmaxf(mx0, lg.x);
    mx1 = fmaxf(mx1, lg.y);
    mx2 = fmaxf(mx2, lg.z);
    mx3 = fmaxf(mx3, lg.w);
  }
#pragma unroll
  for (int off = 32; off >= 1; off >>= 1) {
    mx0 = fmaxf(mx0, __shfl_xor(mx0, off));
    mx1 = fmaxf(mx1, __shfl_xor(mx1, off));
    mx2 = fmaxf(mx2, __shfl_xor(mx2, off));
    mx3 = fmaxf(mx3, __shfl_xor(mx3, off));
  }
  const float mh = (h == 0) ? mx0 : (h == 1) ? mx1 : (h == 2) ? mx2 : mx3;

  // ---- pass 2: weighted accumulation (un-normalized) ----
  float z = 0.f;    // identical across the 16 lanes of a head group
  float ft = 0.f;   // lane's element of [H,D] aggregation
  float ftf = 0.f;  // lane's element of [H,Ed] aggregation (d < 5 only)
  for (int i = beg; i < end; ++i) {
    const int e = perm[i];
    const int s = src[e];
    const float lg = e_logits[(size_t)e * 4 + h];
    const float p = __expf(lg - mh);
    z += p;
    ft += p * feat_p[(size_t)s * 64 + lane];
    if (d < 5) {
      float ep = be;
#pragma unroll
      for (int k = 0; k < 5; ++k) ep += edge_fea[(size_t)e * 5 + k] * wcol[k];
      ftf += p * ep;
    }
  }
  const float inv = (z > 0.f) ? 1.f / z : 0.f;
  ft *= inv;
  ftf *= inv;

  // ---- epilogue: out[h][d] = sum_k cat(ftf,ft)[h][k] * W_out[k][d] + b ----
  float acc = b_out[d] + bias[lane];
#pragma unroll
  for (int k = 0; k < 5; ++k)
    acc += __shfl(ftf, h * 16 + k) * W_out[k * 16 + d];
#pragma unroll
  for (int k = 0; k < 16; ++k)
    acc += __shfl(ft, h * 16 + k) * W_out[(5 + k) * 16 + d];

  out[(size_t)n * 64 + lane] = acc;
}

// ---------------------------------------------------------------------------
extern "C" void kernel_launch(void* const* d_in, const int* in_sizes, int n_in,
                              void* d_out, int out_size, void* d_ws, size_t ws_size,
                              hipStream_t stream) {
  const float* feat     = (const float*)d_in[0];
  const float* edge_fea = (const float*)d_in[1];
  const int*   src      = (const int*)d_in[2];
  const int*   dst      = (const int*)d_in[3];
  const float* W_fc     = (const float*)d_in[4];
  const float* W_edg    = (const float*)d_in[5];
  const float* b_edg    = (const float*)d_in[6];
  const float* attn_l   = (const float*)d_in[7];
  const float* attn_r   = (const float*)d_in[8];
  const float* attn_edg = (const float*)d_in[9];
  const float* W_out    = (const float*)d_in[10];
  const float* b_out    = (const float*)d_in[11];
  const float* bias     = (const float*)d_in[12];

  const int N = in_sizes[0] / 64;
  const int E = in_sizes[2];
  float* out = (float*)d_out;

  // workspace carve-up (256B aligned)
  char* ws = (char*)d_ws;
  size_t off = 0;
  auto alloc = [&](size_t bytes) -> void* {
    void* p = ws + off;
    off = (off + bytes + 255) & ~(size_t)255;
    return p;
  };
  float* feat_p   = (float*)alloc((size_t)N * 64 * 4);
  float* el_er    = (float*)alloc((size_t)N * 8 * 4);
  float* e_logits = (float*)alloc((size_t)E * 4 * 4);
  int*   deg      = (int*)alloc((size_t)N * 4);
  int*   rank     = (int*)alloc((size_t)E * 4);
  int*   row_off  = (int*)alloc((size_t)(N + 1) * 4);
  int*   perm     = (int*)alloc((size_t)E * 4);
  (void)ws_size; (void)n_in; (void)out_size;

  hipMemsetAsync(deg, 0, (size_t)N * 4, stream);

  const int nblk_nodes = (N + 3) / 4;
  const int nblk_edges = (E + 255) / 256;

  node_proj_kernel<<<nblk_nodes, 256, 0, stream>>>(feat, W_fc, attn_l, attn_r,
                                                   feat_p, el_er, N);
  edge_logits_hist_kernel<<<nblk_edges, 256, 0, stream>>>(
      edge_fea, src, dst, el_er, W_edg, b_edg, attn_edg, e_logits, deg, rank, E);
  scan_kernel<<<1, 1024, 0, stream>>>(deg, row_off, N);
  scatter_kernel<<<nblk_edges, 256, 0, stream>>>(dst, row_off, rank, perm, E);
  aggregate_kernel<<<nblk_nodes, 256, 0, stream>>>(
      feat_p, e_logits, edge_fea, src, row_off, perm, W_edg, b_edg, W_out,
      b_out, bias, out, N);
}

// Round 6
// 535.987 us; speedup vs baseline: 1.2854x; 1.2854x over previous
//
#include <hip/hip_runtime.h>
#include <hip/hip_bf16.h>
#include <math.h>

#define NHEADS 4
#define DOUT 16
#define EDIM 5
#define CAP 128   // per-node edge capacity for the LDS fast path

// ---------------------------------------------------------------------------
// K1: feat_p = feat @ W_fc  (N x 64 @ 64 x 64), fused el/er attention dots.
// ---------------------------------------------------------------------------
__global__ __launch_bounds__(256) void node_proj_kernel(
    const float* __restrict__ feat, const float* __restrict__ W_fc,
    const float* __restrict__ attn_l, const float* __restrict__ attn_r,
    float* __restrict__ feat_p, float* __restrict__ el_er, int N) {
  __shared__ float wfc[64 * 64];
  for (int i = threadIdx.x; i < 64 * 64; i += 256) wfc[i] = W_fc[i];
  __syncthreads();
  const int wid  = threadIdx.x >> 6;
  const int lane = threadIdx.x & 63;
  const int n = blockIdx.x * 4 + wid;
  if (n >= N) return;

  const float f = feat[(size_t)n * 64 + lane];
  float acc = 0.f;
#pragma unroll
  for (int k = 0; k < 64; ++k) {
    const float fk = __shfl(f, k);
    acc += fk * wfc[k * 64 + lane];
  }
  feat_p[(size_t)n * 64 + lane] = acc;

  float al = acc * attn_l[lane];
  float ar = acc * attn_r[lane];
#pragma unroll
  for (int off = 1; off < 16; off <<= 1) {
    al += __shfl_xor(al, off);
    ar += __shfl_xor(ar, off);
  }
  if ((lane & 15) == 0) {
    const int h = lane >> 4;
    el_er[(size_t)n * 8 + h]     = al;
    el_er[(size_t)n * 8 + 4 + h] = ar;
  }
}

// ---------------------------------------------------------------------------
// K2: per-edge logits + dst histogram (atomic return value = CSR rank).
// ---------------------------------------------------------------------------
__global__ __launch_bounds__(256) void edge_logits_hist_kernel(
    const float* __restrict__ edge_fea, const int* __restrict__ src,
    const int* __restrict__ dst, const float* __restrict__ el_er,
    const float* __restrict__ W_edg, const float* __restrict__ b_edg,
    const float* __restrict__ attn_edg, float* __restrict__ e_logits,
    int* __restrict__ deg, int* __restrict__ rank, int E) {
  const int e = blockIdx.x * blockDim.x + threadIdx.x;
  if (e >= E) return;
  const int s = src[e];
  const int d = dst[e];
  rank[e] = atomicAdd(&deg[d], 1);

  float ef[5];
#pragma unroll
  for (int k = 0; k < 5; ++k) ef[k] = edge_fea[(size_t)e * 5 + k];

  const float4 elv = *(const float4*)(el_er + (size_t)s * 8);
  const float4 erv = *(const float4*)(el_er + (size_t)d * 8 + 4);
  const float elh[4] = {elv.x, elv.y, elv.z, elv.w};
  const float erh[4] = {erv.x, erv.y, erv.z, erv.w};

  float out[4];
#pragma unroll
  for (int h = 0; h < 4; ++h) {
    float ee = 0.f;
#pragma unroll
    for (int ed = 0; ed < 5; ++ed) {
      float ep = b_edg[h * 5 + ed];
#pragma unroll
      for (int k = 0; k < 5; ++k) ep += ef[k] * W_edg[k * 20 + h * 5 + ed];
      ee += ep * attn_edg[h * 5 + ed];
    }
    const float lg = elh[h] + erh[h] + ee;
    out[h] = (lg > 0.f) ? lg : 0.2f * lg;
  }
  *(float4*)(e_logits + (size_t)e * 4) = make_float4(out[0], out[1], out[2], out[3]);
}

// ---------------------------------------------------------------------------
// K3a/K3b/K3c: hierarchical exclusive scan of deg[N] -> row_off[N+1].
// ---------------------------------------------------------------------------
__global__ __launch_bounds__(256) void scan_reduce_kernel(
    const int* __restrict__ deg, int* __restrict__ partial, int N) {
  const int base = blockIdx.x * 1024;
  int sum = 0;
  for (int i = threadIdx.x; i < 1024; i += 256) {
    const int idx = base + i;
    sum += (idx < N) ? deg[idx] : 0;
  }
#pragma unroll
  for (int off = 32; off >= 1; off >>= 1) sum += __shfl_xor(sum, off);
  __shared__ int ws[4];
  if ((threadIdx.x & 63) == 0) ws[threadIdx.x >> 6] = sum;
  __syncthreads();
  if (threadIdx.x == 0) partial[blockIdx.x] = ws[0] + ws[1] + ws[2] + ws[3];
}

__global__ __launch_bounds__(256) void scan_partials_kernel(
    int* __restrict__ partial, int nb) {
  __shared__ int buf[256];
  __shared__ int carry_s;
  const int t = threadIdx.x;
  if (t == 0) carry_s = 0;
  __syncthreads();
  for (int base = 0; base < nb; base += 256) {
    const int i = base + t;
    const int v = (i < nb) ? partial[i] : 0;
    buf[t] = v;
    __syncthreads();
    for (int off = 1; off < 256; off <<= 1) {
      const int tmp = (t >= off) ? buf[t - off] : 0;
      __syncthreads();
      buf[t] += tmp;
      __syncthreads();
    }
    const int carry = carry_s;
    if (i < nb) partial[i] = carry + buf[t] - v;  // exclusive
    __syncthreads();
    if (t == 255) carry_s = carry + buf[255];
    __syncthreads();
  }
}

__global__ __launch_bounds__(256) void scan_final_kernel(
    const int* __restrict__ deg, const int* __restrict__ partial,
    int* __restrict__ row_off, int N, int E) {
  const int b = blockIdx.x;
  const int t = threadIdx.x;
  const int lane = t & 63;
  const int wid = t >> 6;
  const int base = b * 1024 + t * 4;
  int v[4];
#pragma unroll
  for (int q = 0; q < 4; ++q) {
    const int idx = base + q;
    v[q] = (idx < N) ? deg[idx] : 0;
  }
  const int tsum = v[0] + v[1] + v[2] + v[3];
  int x = tsum;
#pragma unroll
  for (int off = 1; off < 64; off <<= 1) {
    const int tt = __shfl_up(x, off);
    if (lane >= off) x += tt;
  }
  __shared__ int ws[4];
  if (lane == 63) ws[wid] = x;
  __syncthreads();
  int wbase = 0;
  for (int w = 0; w < wid; ++w) wbase += ws[w];
  int run = partial[b] + wbase + (x - tsum);
#pragma unroll
  for (int q = 0; q < 4; ++q) {
    const int idx = base + q;
    if (idx < N) row_off[idx] = run;
    run += v[q];
  }
  if (b == 0 && t == 0) row_off[N] = E;
}

// ---------------------------------------------------------------------------
// K4: scatter edge ids into CSR order (no atomics).
// ---------------------------------------------------------------------------
__global__ __launch_bounds__(256) void scatter_kernel(
    const int* __restrict__ dst, const int* __restrict__ row_off,
    const int* __restrict__ rank, int* __restrict__ perm, int E) {
  const int e = blockIdx.x * blockDim.x + threadIdx.x;
  if (e >= E) return;
  perm[row_off[dst[e]] + rank[e]] = e;
}

// ---------------------------------------------------------------------------
// K5: one wave per destination node, LDS-staged.
//  A1 (lane-parallel): gather perm/src/e_logits/edge_fea -> wave-private LDS,
//      track per-head max.
//  A2 (lane-parallel): p = exp(lg-m) -> LDS; accumulate z, wef (butterfly).
//  B  (serial, unrolled): ft[lane] += p * feat_p[s*64+lane]  (coalesced).
//  Epilogue: ftf = (wef @ W_edg)*inv + b_edg; fused [21]x[21,16] shfl matmul.
// ---------------------------------------------------------------------------
__global__ __launch_bounds__(256) void aggregate_kernel(
    const float* __restrict__ feat_p, const float* __restrict__ e_logits,
    const float* __restrict__ edge_fea, const int* __restrict__ src,
    const int* __restrict__ row_off, const int* __restrict__ perm,
    const float* __restrict__ W_edg, const float* __restrict__ b_edg,
    const float* __restrict__ W_out, const float* __restrict__ b_out,
    const float* __restrict__ bias, float* __restrict__ out, int N) {
  __shared__ float p_lds[4][CAP * 4];
  __shared__ int   s_lds[4][CAP];
  __shared__ float ef_lds[4][5 * CAP];

  const int wave = threadIdx.x >> 6;
  const int lane = threadIdx.x & 63;
  const int n = blockIdx.x * 4 + wave;
  if (n >= N) return;
  const int h = lane >> 4;
  const int d = lane & 15;

  float wcol[5];
  float be = 0.f;
  if (d < 5) {
    be = b_edg[h * 5 + d];
#pragma unroll
    for (int k = 0; k < 5; ++k) wcol[k] = W_edg[k * 20 + h * 5 + d];
  }

  const int beg = row_off[n];
  const int end = row_off[n + 1];
  const int deg = end - beg;

  float ft = 0.f, ftf = 0.f;

  if (deg <= CAP) {
    // ---- A1: lane-parallel gather into LDS + per-head max ----
    float4 mx = make_float4(-INFINITY, -INFINITY, -INFINITY, -INFINITY);
    for (int j0 = 0; j0 < deg; j0 += 64) {
      const int j = j0 + lane;
      if (j < deg) {
        const int e = perm[beg + j];
        const float4 lg = *(const float4*)(e_logits + (size_t)e * 4);
        s_lds[wave][j] = src[e];
        *(float4*)&p_lds[wave][j * 4] = lg;
#pragma unroll
        for (int k = 0; k < 5; ++k)
          ef_lds[wave][k * CAP + j] = edge_fea[(size_t)e * 5 + k];
        mx.x = fmaxf(mx.x, lg.x);
        mx.y = fmaxf(mx.y, lg.y);
        mx.z = fmaxf(mx.z, lg.z);
        mx.w = fmaxf(mx.w, lg.w);
      }
    }
#pragma unroll
    for (int off = 32; off >= 1; off >>= 1) {
      mx.x = fmaxf(mx.x, __shfl_xor(mx.x, off));
      mx.y = fmaxf(mx.y, __shfl_xor(mx.y, off));
      mx.z = fmaxf(mx.z, __shfl_xor(mx.z, off));
      mx.w = fmaxf(mx.w, __shfl_xor(mx.w, off));
    }

    // ---- A2: p = exp(lg - m); accumulate z, wef ----
    float4 z = make_float4(0.f, 0.f, 0.f, 0.f);
    float4 wef[5];
#pragma unroll
    for (int k = 0; k < 5; ++k) wef[k] = make_float4(0.f, 0.f, 0.f, 0.f);
    for (int j0 = 0; j0 < deg; j0 += 64) {
      const int j = j0 + lane;
      if (j < deg) {
        const float4 lg = *(const float4*)&p_lds[wave][j * 4];
        float4 p;
        p.x = __expf(lg.x - mx.x);
        p.y = __expf(lg.y - mx.y);
        p.z = __expf(lg.z - mx.z);
        p.w = __expf(lg.w - mx.w);
        *(float4*)&p_lds[wave][j * 4] = p;
        z.x += p.x; z.y += p.y; z.z += p.z; z.w += p.w;
#pragma unroll
        for (int k = 0; k < 5; ++k) {
          const float efk = ef_lds[wave][k * CAP + j];
          wef[k].x += p.x * efk;
          wef[k].y += p.y * efk;
          wef[k].z += p.z * efk;
          wef[k].w += p.w * efk;
        }
      }
    }
#pragma unroll
    for (int off = 32; off >= 1; off >>= 1) {
      z.x += __shfl_xor(z.x, off);
      z.y += __shfl_xor(z.y, off);
      z.z += __shfl_xor(z.z, off);
      z.w += __shfl_xor(z.w, off);
#pragma unroll
      for (int k = 0; k < 5; ++k) {
        wef[k].x += __shfl_xor(wef[k].x, off);
        wef[k].y += __shfl_xor(wef[k].y, off);
        wef[k].z += __shfl_xor(wef[k].z, off);
        wef[k].w += __shfl_xor(wef[k].w, off);
      }
    }

    // ---- B: serial weighted gather-accumulate (4-way unrolled) ----
    int j = 0;
    for (; j + 4 <= deg; j += 4) {
      const float p0 = p_lds[wave][(j + 0) * 4 + h];
      const float p1 = p_lds[wave][(j + 1) * 4 + h];
      const float p2 = p_lds[wave][(j + 2) * 4 + h];
      const float p3 = p_lds[wave][(j + 3) * 4 + h];
      const int s0 = s_lds[wave][j + 0];
      const int s1 = s_lds[wave][j + 1];
      const int s2 = s_lds[wave][j + 2];
      const int s3 = s_lds[wave][j + 3];
      const float f0 = feat_p[(size_t)s0 * 64 + lane];
      const float f1 = feat_p[(size_t)s1 * 64 + lane];
      const float f2 = feat_p[(size_t)s2 * 64 + lane];
      const float f3 = feat_p[(size_t)s3 * 64 + lane];
      ft += p0 * f0 + p1 * f1 + p2 * f2 + p3 * f3;
    }
    for (; j < deg; ++j) {
      const float p = p_lds[wave][j * 4 + h];
      const int s = s_lds[wave][j];
      ft += p * feat_p[(size_t)s * 64 + lane];
    }

    const float zh = (h == 0) ? z.x : (h == 1) ? z.y : (h == 2) ? z.z : z.w;
    const float inv = (zh > 0.f) ? 1.f / zh : 0.f;
    ft *= inv;
    if (d < 5) {
      float acc = 0.f;
#pragma unroll
      for (int k = 0; k < 5; ++k) {
        const float wk = (h == 0) ? wef[k].x : (h == 1) ? wef[k].y
                        : (h == 2) ? wef[k].z : wef[k].w;
        acc += wk * wcol[k];
      }
      ftf = acc * inv + ((zh > 0.f) ? be : 0.f);
    }
  } else {
    // ---- fallback: serial path (deg > CAP; rare) ----
    float mx0 = -INFINITY, mx1 = -INFINITY, mx2 = -INFINITY, mx3 = -INFINITY;
    for (int i = beg + lane; i < end; i += 64) {
      const int e = perm[i];
      const float4 lg = *(const float4*)(e_logits + (size_t)e * 4);
      mx0 = fmaxf(mx0, lg.x);
      mx1 = fmaxf(mx1, lg.y);
      mx2 = fmaxf(mx2, lg.z);
      mx3 = fmaxf(mx3, lg.w);
    }
#pragma unroll
    for (int off = 32; off >= 1; off >>= 1) {
      mx0 = fmaxf(mx0, __shfl_xor(mx0, off));
      mx1 = fmaxf(mx1, __shfl_xor(mx1, off));
      mx2 = fmaxf(mx2, __shfl_xor(mx2, off));
      mx3 = fmaxf(mx3, __shfl_xor(mx3, off));
    }
    const float mh = (h == 0) ? mx0 : (h == 1) ? mx1 : (h == 2) ? mx2 : mx3;
    float z = 0.f;
    for (int i = beg; i < end; ++i) {
      const int e = perm[i];
      const int s = src[e];
      const float lg = e_logits[(size_t)e * 4 + h];
      const float p = __expf(lg - mh);
      z += p;
      ft += p * feat_p[(size_t)s * 64 + lane];
      if (d < 5) {
        float ep = be;
#pragma unroll
        for (int k = 0; k < 5; ++k) ep += edge_fea[(size_t)e * 5 + k] * wcol[k];
        ftf += p * ep;
      }
    }
    const float inv = (z > 0.f) ? 1.f / z : 0.f;
    ft *= inv;
    ftf *= inv;
  }

  // ---- epilogue: out[h][d] = cat(ftf,ft)[h][:] @ W_out + b ----
  float acc = b_out[d] + bias[lane];
#pragma unroll
  for (int k = 0; k < 5; ++k)
    acc += __shfl(ftf, h * 16 + k) * W_out[k * 16 + d];
#pragma unroll
  for (int k = 0; k < 16; ++k)
    acc += __shfl(ft, h * 16 + k) * W_out[(5 + k) * 16 + d];

  out[(size_t)n * 64 + lane] = acc;
}

// ---------------------------------------------------------------------------
extern "C" void kernel_launch(void* const* d_in, const int* in_sizes, int n_in,
                              void* d_out, int out_size, void* d_ws, size_t ws_size,
                              hipStream_t stream) {
  const float* feat     = (const float*)d_in[0];
  const float* edge_fea = (const float*)d_in[1];
  const int*   src      = (const int*)d_in[2];
  const int*   dst      = (const int*)d_in[3];
  const float* W_fc     = (const float*)d_in[4];
  const float* W_edg    = (const float*)d_in[5];
  const float* b_edg    = (const float*)d_in[6];
  const float* attn_l   = (const float*)d_in[7];
  const float* attn_r   = (const float*)d_in[8];
  const float* attn_edg = (const float*)d_in[9];
  const float* W_out    = (const float*)d_in[10];
  const float* b_out    = (const float*)d_in[11];
  const float* bias     = (const float*)d_in[12];

  const int N = in_sizes[0] / 64;
  const int E = in_sizes[2];
  float* out = (float*)d_out;

  char* ws = (char*)d_ws;
  size_t off = 0;
  auto alloc = [&](size_t bytes) -> void* {
    void* p = ws + off;
    off = (off + bytes + 255) & ~(size_t)255;
    return p;
  };
  float* feat_p   = (float*)alloc((size_t)N * 64 * 4);
  float* el_er    = (float*)alloc((size_t)N * 8 * 4);
  float* e_logits = (float*)alloc((size_t)E * 4 * 4);
  int*   deg      = (int*)alloc((size_t)N * 4);
  int*   rank     = (int*)alloc((size_t)E * 4);
  int*   row_off  = (int*)alloc((size_t)(N + 1) * 4);
  int*   perm     = (int*)alloc((size_t)E * 4);
  int*   partial  = (int*)alloc((size_t)1024 * 4);
  (void)ws_size; (void)n_in; (void)out_size;

  hipMemsetAsync(deg, 0, (size_t)N * 4, stream);

  const int nblk_nodes = (N + 3) / 4;
  const int nblk_edges = (E + 255) / 256;
  const int nb_scan = (N + 1023) / 1024;

  node_proj_kernel<<<nblk_nodes, 256, 0, stream>>>(feat, W_fc, attn_l, attn_r,
                                                   feat_p, el_er, N);
  edge_logits_hist_kernel<<<nblk_edges, 256, 0, stream>>>(
      edge_fea, src, dst, el_er, W_edg, b_edg, attn_edg, e_logits, deg, rank, E);
  scan_reduce_kernel<<<nb_scan, 256, 0, stream>>>(deg, partial, N);
  scan_partials_kernel<<<1, 256, 0, stream>>>(partial, nb_scan);
  scan_final_kernel<<<nb_scan, 256, 0, stream>>>(deg, partial, row_off, N, E);
  scatter_kernel<<<nblk_edges, 256, 0, stream>>>(dst, row_off, rank, perm, E);
  aggregate_kernel<<<nblk_nodes, 256, 0, stream>>>(
      feat_p, e_logits, edge_fea, src, row_off, perm, W_edg, b_edg, W_out,
      b_out, bias, out, N);
}